// Round 14
// baseline (89.864 us; speedup 1.0000x reference)
//
#include <hip/hip_runtime.h>
#include <hip/hip_bf16.h>

#define L2E  1.4426950408889634f
#define LN2f 0.6931471805599453f

typedef __attribute__((ext_vector_type(4))) float f32x4;
typedef __attribute__((ext_vector_type(4), aligned(4))) float f32x4u;  // 4B-aligned loads (t*60 is not 16B-aligned)
typedef __attribute__((ext_vector_type(4))) short s16x4;

#if __has_builtin(__builtin_amdgcn_mfma_f32_16x16x16bf16_1k)
__device__ __forceinline__ f32x4 mfma16(s16x4 a, s16x4 b) {
  f32x4 z = {0.f, 0.f, 0.f, 0.f};
  return __builtin_amdgcn_mfma_f32_16x16x16bf16_1k(a, b, z, 0, 0, 0);
}
#else
__device__ __forceinline__ f32x4 mfma16(s16x4 a, s16x4 b) {
  f32x4 d = {0.f, 0.f, 0.f, 0.f};
  asm volatile("s_nop 1\n\t"
               "v_mfma_f32_16x16x16_bf16 %0, %1, %2, %0\n\t"
               "s_nop 7\n\ts_nop 7"
               : "+v"(d) : "v"(a), "v"(b));
  return d;
}
#endif

__device__ __forceinline__ short f2bf(float f) {
  __hip_bfloat16 h = __float2bfloat16(f);
  return (short)__builtin_bit_cast(unsigned short, h);
}

// y component select (compile-time folds). fwd: t ≡ TL (mod 8); yq0=[tq..tq+3], yq1=[tq+4..tq+7]
#define YSELF(TL) ( ((TL)&3)==0 ? (((TL)&4)? yq1.x : yq0.x) : \
                    ((TL)&3)==1 ? (((TL)&4)? yq1.y : yq0.y) : \
                    ((TL)&3)==2 ? (((TL)&4)? yq1.z : yq0.z) : \
                                  (((TL)&4)? yq1.w : yq0.w) )
// bwd: t = t0-TL, t0 ≡ 7 (mod 8): component 3-(TL&3), half (TL&4)? yq0 : yq1
#define YSELB(TL) ( ((TL)&3)==0 ? (((TL)&4)? yq0.w : yq1.w) : \
                    ((TL)&3)==1 ? (((TL)&4)? yq0.z : yq1.z) : \
                    ((TL)&3)==2 ? (((TL)&4)? yq0.y : yq1.y) : \
                                  (((TL)&4)? yq0.x : yq1.x) )

// fwd step t: v_t = mask_t ? diag(p_t)·W^T·v_{t-1} : v_{t-1}
// D = A(=W^T, static)·B(state cols); lane holds D rows r0..r0+3 of column (lane&15).
#define STEPF(TL) do { \
    const f32x4 e4_ = ering[(TL) & 7]; \
    ering[(TL) & 7] = *(const f32x4u*)(ebc + ((TL) + 8) * 60); \
    const int yv_ = YSELF(TL); \
    const float u0_ = sel3 ? e4_.y : e4_.x; \
    const float u1_ = sel3 ? e4_.z : e4_.y; \
    const float u2_ = sel3 ? e4_.w : e4_.z; \
    const float u3_ = e4_.w; \
    const f32x4 dd_ = mfma16(af, b16); \
    const float p0_ = exp2f(u0_ * L2E), p1_ = exp2f(u1_ * L2E); \
    const float p2_ = exp2f(u2_ * L2E), p3_ = exp2f(u3_ * L2E); \
    const bool mk_ = (yv_ != 15); \
    st0 = mk_ ? dd_[0] * p0_ : st0; \
    st1 = mk_ ? dd_[1] * p1_ : st1; \
    st2 = mk_ ? dd_[2] * p2_ : st2; \
    st3 = mk_ ? dd_[3] * p3_ : st3; \
    const float v01_ = (yv_ & 1) ? u1_ : u0_; \
    const float v23_ = (yv_ & 1) ? u3_ : u2_; \
    const float vv_ = (yv_ & 2) ? v23_ : v01_; \
    eacc += (mk_ & ((yv_ >> 2) == g4)) ? vv_ : 0.f; \
    if (((TL) & 7) == 7) { \
      yq0 = *(const int4*)(ybc + ((TL) + 1) * 4); \
      yq1 = *(const int4*)(ybc + ((TL) + 5) * 4); \
      float mx_ = fmaxf(fmaxf(st0, st1), fmaxf(st2, st3)); \
      mx_ = fmaxf(mx_, __shfl_xor(mx_, 16, 64)); \
      mx_ = fmaxf(mx_, __shfl_xor(mx_, 32, 64)); \
      const float rs_ = __builtin_amdgcn_rcpf(mx_); \
      st0 *= rs_; st1 *= rs_; st2 *= rs_; st3 *= rs_; \
      M += log2f(mx_); \
    } \
    b16[0] = f2bf(st0); b16[1] = f2bf(st1); \
    b16[2] = f2bf(st2); b16[3] = f2bf(st3); \
  } while (0)

// bwd step t: u_{t-1} = mask_t ? W·(p_t ∘ u_t) : u_t   (A = W static; scale before MFMA)
#define STEPB(TL) do { \
    const f32x4 e4_ = ering[7 - ((TL) & 7)]; \
    ering[7 - ((TL) & 7)] = *(const f32x4u*)(ebc - ((TL) + 8) * 60); \
    const int yv_ = YSELB(TL); \
    const float u0_ = sel3 ? e4_.y : e4_.x; \
    const float u1_ = sel3 ? e4_.z : e4_.y; \
    const float u2_ = sel3 ? e4_.w : e4_.z; \
    const float u3_ = e4_.w; \
    const float p0_ = exp2f(u0_ * L2E), p1_ = exp2f(u1_ * L2E); \
    const float p2_ = exp2f(u2_ * L2E), p3_ = exp2f(u3_ * L2E); \
    b16[0] = f2bf(st0 * p0_); b16[1] = f2bf(st1 * p1_); \
    b16[2] = f2bf(st2 * p2_); b16[3] = f2bf(st3 * p3_); \
    const f32x4 dd_ = mfma16(af, b16); \
    const bool mk_ = (yv_ != 15); \
    st0 = mk_ ? dd_[0] : st0; \
    st1 = mk_ ? dd_[1] : st1; \
    st2 = mk_ ? dd_[2] : st2; \
    st3 = mk_ ? dd_[3] : st3; \
    const float v01_ = (yv_ & 1) ? u1_ : u0_; \
    const float v23_ = (yv_ & 1) ? u3_ : u2_; \
    const float vv_ = (yv_ & 2) ? v23_ : v01_; \
    eacc += (mk_ & ((yv_ >> 2) == g4)) ? vv_ : 0.f; \
    if (((TL) & 7) == 7) { \
      yq0 = *(const int4*)(ybc - ((TL) + 8) * 4); \
      yq1 = *(const int4*)(ybc - ((TL) + 4) * 4); \
      float mx_ = fmaxf(fmaxf(st0, st1), fmaxf(st2, st3)); \
      mx_ = fmaxf(mx_, __shfl_xor(mx_, 16, 64)); \
      mx_ = fmaxf(mx_, __shfl_xor(mx_, 32, 64)); \
      const float rs_ = __builtin_amdgcn_rcpf(mx_); \
      st0 *= rs_; st1 *= rs_; st2 *= rs_; st3 *= rs_; \
      M += log2f(mx_); \
    } \
  } while (0)

#define FB32_ { STEPF(0); STEPF(1); STEPF(2); STEPF(3); STEPF(4); STEPF(5); STEPF(6); STEPF(7); \
                STEPF(8); STEPF(9); STEPF(10); STEPF(11); STEPF(12); STEPF(13); STEPF(14); STEPF(15); \
                STEPF(16); STEPF(17); STEPF(18); STEPF(19); STEPF(20); STEPF(21); STEPF(22); STEPF(23); \
                STEPF(24); STEPF(25); STEPF(26); STEPF(27); STEPF(28); STEPF(29); STEPF(30); STEPF(31); }
#define FB31_ { STEPF(1); STEPF(2); STEPF(3); STEPF(4); STEPF(5); STEPF(6); STEPF(7); \
                STEPF(8); STEPF(9); STEPF(10); STEPF(11); STEPF(12); STEPF(13); STEPF(14); STEPF(15); \
                STEPF(16); STEPF(17); STEPF(18); STEPF(19); STEPF(20); STEPF(21); STEPF(22); STEPF(23); \
                STEPF(24); STEPF(25); STEPF(26); STEPF(27); STEPF(28); STEPF(29); STEPF(30); STEPF(31); }
#define BB32_ { STEPB(0); STEPB(1); STEPB(2); STEPB(3); STEPB(4); STEPB(5); STEPB(6); STEPB(7); \
                STEPB(8); STEPB(9); STEPB(10); STEPB(11); STEPB(12); STEPB(13); STEPB(14); STEPB(15); \
                STEPB(16); STEPB(17); STEPB(18); STEPB(19); STEPB(20); STEPB(21); STEPB(22); STEPB(23); \
                STEPB(24); STEPB(25); STEPB(26); STEPB(27); STEPB(28); STEPB(29); STEPB(30); STEPB(31); }

__global__ __launch_bounds__(256, 2)
void crf_mm4(const float* __restrict__ logits, const int* __restrict__ yg,
             const float* __restrict__ trans, float* __restrict__ out) {
  __shared__ float Tl[240];
  __shared__ float comb[8][2][16];
  __shared__ float pathE[8][2];
  __shared__ float transS[8];
  __shared__ float blks[8];

  const int tid = threadIdx.x;
  if (tid < 225) Tl[tid] = trans[tid];
  __syncthreads();

  const char* yub0 = (const char*)yg + (size_t)blockIdx.x * (8 * 2048);

  // ---- transition part of path score (coalesced global y; verified R8) ----
  {
    const int q = tid >> 5, l32 = tid & 31;
    const int* ys = (const int*)(yub0 + q * 2048);
    float acc = 0.f;
    #pragma unroll
    for (int m = 0; m < 16; ++m) {
      const int t = 1 + l32 + 32 * m;
      if (t < 512) {
        const int yc = ys[t], yp = ys[t - 1];
        if (yc < 15 && yp < 15) acc += Tl[yp * 15 + yc];
      }
    }
    #pragma unroll
    for (int k = 1; k < 32; k <<= 1) acc += __shfl_xor(acc, k, 32);
    if (l32 == 0) transS[q] = acc;
  }

  // ---- wave -> (seq group, direction); 4 chains ride MFMA columns 0..3 ----
  const int wv = tid >> 6, lane = tid & 63;
  const int c  = lane & 15;                 // MFMA column (chain for c<4; dup of 3 else) / A row
  const int g4 = lane >> 4;                 // row block: rows r0..r0+3
  const int r0 = g4 * 4;
  const bool sel3 = (g4 == 3);              // rows 12..15: shifted e-load (avoids OOB at t=511)
  const int cc = (c < 4) ? c : 3;
  const int grp = wv >> 1;
  const bool isFwd = (wv & 1) == 0;
  const int dir = isFwd ? 0 : 1;
  const size_t seq = (size_t)(blockIdx.x * 8 + grp * 4 + cc);
  const int off4 = sel3 ? 44 : r0 * 4;      // g4=3 reads rows 11..14; shift-select fixes rows

  const char* ebc = (const char*)logits + seq * 30720 + off4;
  const char* ybc = (const char*)yg + seq * 2048;

  // A static (bf16): fwd A[m][k] = W[k][m] = exp2(T[k][m]); bwd A[m][k] = W[m][k].
  // Frag: m = lane&15, k = r0+q (R7-verified layout). Rows/cols >= 15 are 0.
  int2 afi;
  {
    short as0, as1, as2, as3;
    short* asp[4] = {&as0, &as1, &as2, &as3};
    #pragma unroll
    for (int q = 0; q < 4; ++q) {
      const int k = r0 + q;
      const bool valid = (c < 15) && (k < 15);
      const int idx = isFwd ? (k * 15 + c) : (c * 15 + k);
      *asp[q] = f2bf(valid ? exp2f(Tl[valid ? idx : 0] * L2E) : 0.f);
    }
    afi.x = (int)(unsigned short)as0 | ((int)(unsigned short)as1 << 16);
    afi.y = (int)(unsigned short)as2 | ((int)(unsigned short)as3 << 16);
  }
  asm volatile("" : "+v"(afi.x), "+v"(afi.y));   // pin A (R4/R5 remat lesson)
  const s16x4 af = __builtin_bit_cast(s16x4, afi);

  f32x4 ering[8];
  int4 yq0, yq1;
  s16x4 b16;
  float st0, st1, st2, st3, M, eacc;

  if (isFwd) {
    // ring prefill t=1..8 (slot = t&7); y octave [0..7]
    ering[1] = *(const f32x4u*)(ebc + 60);
    ering[2] = *(const f32x4u*)(ebc + 120);
    ering[3] = *(const f32x4u*)(ebc + 180);
    ering[4] = *(const f32x4u*)(ebc + 240);
    ering[5] = *(const f32x4u*)(ebc + 300);
    ering[6] = *(const f32x4u*)(ebc + 360);
    ering[7] = *(const f32x4u*)(ebc + 420);
    ering[0] = *(const f32x4u*)(ebc + 480);
    yq0 = *(const int4*)(ybc);
    yq1 = *(const int4*)(ybc + 16);
    const f32x4 ez = *(const f32x4u*)(ebc);          // t=0
    const float u0_ = sel3 ? ez.y : ez.x;
    const float u1_ = sel3 ? ez.z : ez.y;
    const float u2_ = sel3 ? ez.w : ez.z;
    const float u3_ = ez.w;
    float mx_ = fmaxf(fmaxf(u0_, u1_), fmaxf(u2_, sel3 ? u2_ : u3_));
    mx_ = fmaxf(mx_, __shfl_xor(mx_, 16, 64));
    mx_ = fmaxf(mx_, __shfl_xor(mx_, 32, 64));
    st0 = exp2f((u0_ - mx_) * L2E);
    st1 = exp2f((u1_ - mx_) * L2E);
    st2 = exp2f((u2_ - mx_) * L2E);
    st3 = sel3 ? 0.f : exp2f((u3_ - mx_) * L2E);     // row 15 stays 0
    M = mx_ * L2E;
    b16[0] = f2bf(st0); b16[1] = f2bf(st1); b16[2] = f2bf(st2); b16[3] = f2bf(st3);
    const int y0_ = yq0.x;                            // emission at t=0
    const bool mk0 = (y0_ != 15);
    const float v01_ = (y0_ & 1) ? u1_ : u0_;
    const float v23_ = (y0_ & 1) ? u3_ : u2_;
    const float vv_ = (y0_ & 2) ? v23_ : v01_;
    eacc = (mk0 & ((y0_ >> 2) == g4)) ? vv_ : 0.f;

    FB31_;                                            // t = 1..31
    #pragma unroll 1
    for (int b = 0; b < 7; ++b) { ebc += 1920; ybc += 128; FB32_; }   // t = 32..255
  } else {
    ebc += 511 * 60;                                  // anchor t=511
    ybc += 511 * 4;
    ering[7] = *(const f32x4u*)(ebc);
    ering[6] = *(const f32x4u*)(ebc - 60);
    ering[5] = *(const f32x4u*)(ebc - 120);
    ering[4] = *(const f32x4u*)(ebc - 180);
    ering[3] = *(const f32x4u*)(ebc - 240);
    ering[2] = *(const f32x4u*)(ebc - 300);
    ering[1] = *(const f32x4u*)(ebc - 360);
    ering[0] = *(const f32x4u*)(ebc - 420);
    yq0 = *(const int4*)(ybc - 28);                   // y[504..507]
    yq1 = *(const int4*)(ybc - 12);                   // y[508..511]
    st0 = 1.f; st1 = 1.f; st2 = 1.f; st3 = sel3 ? 0.f : 1.f;   // u_511 = 1 (valid rows)
    M = 0.f; eacc = 0.f;
    #pragma unroll 1
    for (int b = 0; b < 8; ++b) { BB32_; ebc -= 1920; ybc -= 128; }   // t = 511..256
  }

  // ---- write per-sequence results ----
  if (c < 4) {
    float* cb = &comb[grp * 4 + c][dir][0];
    cb[r0 + 0] = M + log2f(st0);
    cb[r0 + 1] = M + log2f(st1);
    cb[r0 + 2] = M + log2f(st2);
    if (!sel3) cb[r0 + 3] = M + log2f(st3);
  }
  eacc += __shfl_xor(eacc, 16, 64);
  eacc += __shfl_xor(eacc, 32, 64);
  if (c < 4 && g4 == 0) pathE[grp * 4 + c][dir] = eacc;

  __syncthreads();

  // ---- per-sequence combine: logZ = lse_i(log2 v_255[i] + log2 u_255[i]) ----
  if (tid < 8) {
    float mx = -3.0e38f; float s[15];
    #pragma unroll
    for (int i = 0; i < 15; ++i) {
      s[i] = comb[tid][0][i] + comb[tid][1][i];
      mx = fmaxf(mx, s[i]);
    }
    float sum = 0.f;
    #pragma unroll
    for (int i = 0; i < 15; ++i) sum += exp2f(s[i] - mx);
    const float logZ = (mx + log2f(sum)) * LN2f;
    const float path = pathE[tid][0] + pathE[tid][1] + transS[tid];
    float nll = logZ - path;
    nll = fminf(fmaxf(nll, 0.f), 1000000.f);
    blks[tid] = nll;
  }
  __syncthreads();
  if (tid == 0) {
    const float tot = (blks[0] + blks[1]) + (blks[2] + blks[3]) +
                      (blks[4] + blks[5]) + (blks[6] + blks[7]);
    atomicAdd(out, tot * (1.0f / 4096.0f));
  }
}

extern "C" void kernel_launch(void* const* d_in, const int* in_sizes, int n_in,
                              void* d_out, int out_size, void* d_ws, size_t ws_size,
                              hipStream_t stream) {
  const float* logits = (const float*)d_in[0];   // (4096, 512, 15) f32
  const int*   y      = (const int*)d_in[1];     // (4096, 512) i32
  const float* trans  = (const float*)d_in[2];   // (15, 15) f32
  float* out = (float*)d_out;

  hipMemsetAsync(out, 0, sizeof(float), stream);

  const int B = in_sizes[1] / 512;               // 4096
  crf_mm4<<<dim3(B / 8), dim3(256), 0, stream>>>(logits, y, trans, out);
}